// Round 1
// 524.072 us; speedup vs baseline: 1.0537x; 1.0537x over previous
//
#include <hip/hip_runtime.h>

#define NUSERS 100000
#define NITEMS 50000
#define NTOT   150000
#define NEDGE  1000000
#define NTILE  9375   // NTOT / 16

typedef unsigned int uint32;
typedef __attribute__((ext_vector_type(8))) short short8;
typedef __attribute__((ext_vector_type(4))) float f32x4;

__device__ __forceinline__ unsigned short f2bf(float f) {
  unsigned int u = __float_as_uint(f);
  u += 0x7FFFu + ((u >> 16) & 1u);   // round-to-nearest-even
  return (unsigned short)(u >> 16);
}
__device__ __forceinline__ uint32 pack2bf(float a, float b) {
  return (uint32)f2bf(a) | ((uint32)f2bf(b) << 16);
}
__device__ __forceinline__ float bf_lo(uint32 u) { return __uint_as_float(u << 16); }
__device__ __forceinline__ float bf_hi(uint32 u) { return __uint_as_float(u & 0xFFFF0000u); }

// ---- init: embb0 = bf16-pair packed copy of concat(user,item). No fp32 out
// write anymore: the final sum kernel reads ue/ie directly. ----
__global__ void k_init(const float* __restrict__ ue, const float* __restrict__ ie,
                       uint32* __restrict__ embb) {
  int i = blockIdx.x * 256 + threadIdx.x;  // float4 index
  if (i >= NTOT * 16) return;
  float4 v = (i < NUSERS * 16) ? ((const float4*)ue)[i]
                               : ((const float4*)ie)[i - NUSERS * 16];
  uint2 pk;
  pk.x = pack2bf(v.x, v.y);
  pk.y = pack2bf(v.z, v.w);
  ((uint2*)embb)[i] = pk;
}

// ---- W pack: Wbg[l*6144 + mat*2048 + n*32 + k2] = bf16(W[2k2][n], W[2k2+1][n]) ----
__global__ void k_wpack(const float* __restrict__ Wq, const float* __restrict__ Wk,
                        const float* __restrict__ Wv, uint32* __restrict__ Wbg) {
  int t = blockIdx.x * 256 + threadIdx.x;
  if (t >= 12288) return;
  int l = t / 6144, rem = t % 6144, mat = rem / 2048, j = rem % 2048;
  int n = j >> 5, k2 = j & 31;
  const float* W = (mat == 0 ? Wq : mat == 1 ? Wk : Wv) + l * 4096;
  Wbg[t] = pack2bf(W[k2 * 128 + n], W[k2 * 128 + 64 + n]);
}

// ---- CSR build: histogram -> scan -> fill ----
__global__ void k_hist(const int* __restrict__ rows, int* __restrict__ cnt) {
  int e = blockIdx.x * 256 + threadIdx.x;
  if (e < NEDGE) atomicAdd(&cnt[rows[e]], 1);
}

__global__ void k_scan1(const int* __restrict__ cnt, int* __restrict__ partial,
                        int* __restrict__ blocksums) {
  __shared__ int s[256];
  int t = threadIdx.x, b = blockIdx.x;
  int base = b * 2048 + t * 8;
  int pre[8]; int sum = 0;
  #pragma unroll
  for (int j = 0; j < 8; ++j) {
    int idx = base + j;
    int x = (idx < NTOT) ? cnt[idx] : 0;
    pre[j] = sum; sum += x;
  }
  s[t] = sum; __syncthreads();
  for (int off = 1; off < 256; off <<= 1) {
    int x = (t >= off) ? s[t - off] : 0;
    __syncthreads(); s[t] += x; __syncthreads();
  }
  int excl = s[t] - sum;
  #pragma unroll
  for (int j = 0; j < 8; ++j) {
    int idx = base + j;
    if (idx < NTOT) partial[idx] = excl + pre[j];
  }
  if (t == 255) blocksums[b] = s[255];
}

__global__ void k_scan2(const int* __restrict__ blocksums, int* __restrict__ blockoffs, int nblk) {
  __shared__ int s[128];
  int t = threadIdx.x;
  int x = (t < nblk) ? blocksums[t] : 0;
  s[t] = x; __syncthreads();
  for (int off = 1; off < 128; off <<= 1) {
    int y = (t >= off) ? s[t - off] : 0;
    __syncthreads(); s[t] += y; __syncthreads();
  }
  if (t < nblk) blockoffs[t] = s[t] - x;
}

__global__ void k_scan3(int* __restrict__ row_ptr, const int* __restrict__ blockoffs,
                        int* __restrict__ cursor) {
  int i = blockIdx.x * 256 + threadIdx.x;
  if (i < NTOT) {
    int v = row_ptr[i] + blockoffs[i >> 11];
    row_ptr[i] = v; cursor[i] = v;
  }
  if (i == 0) row_ptr[NTOT] = NEDGE;
}

__global__ void k_fill(const int* __restrict__ rows, const int* __restrict__ cols,
                       const float* __restrict__ vals, int* __restrict__ cursor,
                       int* __restrict__ ecols, float* __restrict__ evals) {
  int e = blockIdx.x * 256 + threadIdx.x;
  if (e >= NEDGE) return;
  int r = rows[e];
  int pos = atomicAdd(&cursor[r], 1);
  ecols[pos] = cols[e];
  evals[pos] = vals[e];
}

// ---- QKV v5: MFMA. wave = 16-node tile. No LDS in main loop. ----
__global__ void __launch_bounds__(256) k_qkv(const uint32* __restrict__ embb,
    const uint32* __restrict__ Wbg, float* __restrict__ Q, uint32* __restrict__ KVb) {
  __shared__ float scr[4][2][16][68];  // [wave][K/V][node][dim(+pad)] = 34816 B
  int t = threadIdx.x;
  int wave = t >> 6, lane = t & 63;
  int tile = blockIdx.x * 4 + wave;
  if (tile >= NTILE) return;
  int c = lane & 15, quad = lane >> 4;
  int nodeBase = tile * 16;
  const uint32* arow = embb + (nodeBase + c) * 32 + quad * 4;
  uint4 a0u = *(const uint4*)arow;          // dims quad*8 .. +7
  uint4 a1u = *(const uint4*)(arow + 16);   // dims 32+quad*8 .. +7
  short8 a0 = *(short8*)&a0u;
  short8 a1 = *(short8*)&a1u;
  float (*SK)[68] = scr[wave][0];
  float (*SV)[68] = scr[wave][1];
  const uint32* wbase = Wbg + c * 32 + quad * 4;
  #pragma unroll
  for (int mat = 0; mat < 3; ++mat) {
    f32x4 acc[4];
    #pragma unroll
    for (int nt = 0; nt < 4; ++nt) acc[nt] = (f32x4){0.f, 0.f, 0.f, 0.f};
    const uint32* wb = wbase + mat * 2048;
    #pragma unroll
    for (int nt = 0; nt < 4; ++nt) {
      uint4 b0u = *(const uint4*)(wb + nt * 512);        // kh=0
      uint4 b1u = *(const uint4*)(wb + nt * 512 + 16);   // kh=1
      short8 b0 = *(short8*)&b0u;
      short8 b1 = *(short8*)&b1u;
      acc[nt] = __builtin_amdgcn_mfma_f32_16x16x32_bf16(a0, b0, acc[nt], 0, 0, 0);
      acc[nt] = __builtin_amdgcn_mfma_f32_16x16x32_bf16(a1, b1, acc[nt], 0, 0, 0);
    }
    float (*S)[68] = (mat == 2) ? SV : SK;   // Q and K reuse SK
    #pragma unroll
    for (int nt = 0; nt < 4; ++nt)
      #pragma unroll
      for (int r = 0; r < 4; ++r)
        S[quad * 4 + r][nt * 16 + c] = acc[nt][r];
    if (mat == 0) {
      #pragma unroll
      for (int i = 0; i < 4; ++i) {
        int node = i * 4 + quad;
        f32x4 q4 = *(f32x4*)&SK[node][c * 4];
        *(f32x4*)&Q[(nodeBase + node) * 64 + c * 4] = q4;
      }
    } else if (mat == 2) {
      #pragma unroll
      for (int i = 0; i < 4; ++i) {
        int node = i * 4 + quad;
        f32x4 K4 = *(f32x4*)&SK[node][c * 4];
        f32x4 V4 = *(f32x4*)&SV[node][c * 4];
        uint4 o;
        o.x = pack2bf(K4[0], K4[1]);
        o.y = pack2bf(K4[2], K4[3]);
        o.z = pack2bf(V4[0], V4[1]);
        o.w = pack2bf(V4[2], V4[3]);
        *(uint4*)&KVb[(nodeBase + node) * 64 + c * 4] = o;
      }
    }
  }
}

// ---- GT layer: wave = node; 4 edge-slots x 16 lanes. ----
// New in this round: (a) no acc_out RMW (final sum is fused into last GCN);
// (b) the per-iteration ecols load is replaced by a single coalesced 64-edge
// preload + __shfl (ds_bpermute) — removes one global round-trip from every
// iteration's addr->gather dependency chain (degree avg 6.7 => ~2 iters/wave,
// so this latency was on nearly every wave's critical path).
__global__ void __launch_bounds__(256) k_gt(const float* __restrict__ Q,
    const uint32* __restrict__ KVb, const int* __restrict__ row_ptr,
    const int* __restrict__ ecols, float* __restrict__ emb_out,
    uint32* __restrict__ embb_out) {
  int t = threadIdx.x;
  int n = blockIdx.x * 4 + (t >> 6);
  if (n >= NTOT) return;
  int lane = t & 63;
  int es = lane >> 4;
  int dl = lane & 15;
  float4 q4 = *(const float4*)&Q[n * 64 + dl * 4];
  int s     = __builtin_amdgcn_readfirstlane(row_ptr[n]);
  int e_end = __builtin_amdgcn_readfirstlane(row_ptr[n + 1]);
  int cnt = e_end - s;
  // bulk preload of up to 64 edge columns (max degree of this graph << 64;
  // guarded fallback below keeps correctness for arbitrary degree)
  int li = s + lane;
  int cv = ecols[li < NEDGE ? li : NEDGE - 1];
  float den = 0.f;
  float4 acc = make_float4(0.f, 0.f, 0.f, 0.f);
  #pragma unroll 2
  for (int base = 0; base < cnt; base += 4) {
    int i = base + es;
    int cc;
    if (base < 64) cc = __shfl(cv, i & 63);
    else           cc = (i < cnt) ? ecols[s + i] : 0;
    float ex = 0.f;
    float4 v4 = make_float4(0.f, 0.f, 0.f, 0.f);
    if (i < cnt) {
      uint4 w = *(const uint4*)&KVb[cc * 64 + dl * 4];
      float kx = bf_lo(w.x), ky = bf_hi(w.x);
      float kz = bf_lo(w.y), kw = bf_hi(w.y);
      v4.x = bf_lo(w.z); v4.y = bf_hi(w.z);
      v4.z = bf_lo(w.w); v4.w = bf_hi(w.w);
      float x = q4.x * kx + q4.y * ky + q4.z * kz + q4.w * kw;
      x += __shfl_xor(x, 1);
      x += __shfl_xor(x, 2);
      x = fminf(fmaxf(x, -10.f), 10.f);
      ex = __expf(x);
    }
    den += ex;
    acc.x = fmaf(ex, v4.x, acc.x);
    acc.y = fmaf(ex, v4.y, acc.y);
    acc.z = fmaf(ex, v4.z, acc.z);
    acc.w = fmaf(ex, v4.w, acc.w);
  }
  #pragma unroll
  for (int off = 16; off <= 32; off <<= 1) {
    den  += __shfl_xor(den, off);
    acc.x += __shfl_xor(acc.x, off);
    acc.y += __shfl_xor(acc.y, off);
    acc.z += __shfl_xor(acc.z, off);
    acc.w += __shfl_xor(acc.w, off);
  }
  float inv = 1.f / (den + 1e-8f);
  float4 r = make_float4(acc.x * inv, acc.y * inv, acc.z * inv, acc.w * inv);
  if (es == 0) {
    *(float4*)&emb_out[n * 64 + dl * 4] = r;
  } else if (es == 1) {
    uint2 pk;
    pk.x = pack2bf(r.x, r.y);
    pk.y = pack2bf(r.z, r.w);
    *(uint2*)&embb_out[n * 32 + dl * 2] = pk;
  }
}

// ---- GCN layer (spmm): wave per node, lane = dim, 8-wide predicated body.
// Clamped dead-slot indices alias the j=0 edge => L1 hits, weights zeroed.
// FINAL=1 fuses the 5-term output sum: out = cat(ue,ie) + GT1 + GT2 + GCN1 + GCN2. ----
template<int FINAL>
__global__ void __launch_bounds__(256) k_gcn(const float* __restrict__ emb,
    const int* __restrict__ row_ptr, const int* __restrict__ ecols,
    const float* __restrict__ evals, float* __restrict__ emb_out,
    const float* __restrict__ ue, const float* __restrict__ ie,
    const float* __restrict__ add1, const float* __restrict__ add2) {
  int t = threadIdx.x;
  int n = blockIdx.x * 4 + (t >> 6);
  if (n >= NTOT) return;
  int lane = t & 63;
  int s     = __builtin_amdgcn_readfirstlane(row_ptr[n]);
  int e_end = __builtin_amdgcn_readfirstlane(row_ptr[n + 1]);
  float a[8];
  #pragma unroll
  for (int j = 0; j < 8; ++j) a[j] = 0.f;
  for (int p = s; p < e_end; p += 8) {
    #pragma unroll
    for (int j = 0; j < 8; ++j) {
      int pj = p + j;
      int pc = (pj < e_end) ? pj : s;          // clamp: dead slots re-hit edge s (L1)
      float w = (pj < e_end) ? evals[pc] : 0.f;
      int c = ecols[pc];
      a[j] = fmaf(w, emb[c * 64 + lane], a[j]);
    }
  }
  float acc = ((a[0] + a[1]) + (a[2] + a[3])) + ((a[4] + a[5]) + (a[6] + a[7]));
  int base = n * 64 + lane;
  if (FINAL) {
    float b = (n < NUSERS) ? ue[base] : ie[base - NUSERS * 64];
    acc += b + add1[base] + add2[base] + emb[base];   // emb[base] = GCN1's own row
  }
  emb_out[base] = acc;
}

extern "C" void kernel_launch(void* const* d_in, const int* in_sizes, int n_in,
                              void* d_out, int out_size, void* d_ws, size_t ws_size,
                              hipStream_t stream) {
  const int*   rows = (const int*)d_in[0];
  const int*   cols = (const int*)d_in[1];
  const float* vals = (const float*)d_in[2];
  const float* ue   = (const float*)d_in[3];
  const float* ie   = (const float*)d_in[4];
  const float* Wq   = (const float*)d_in[5];
  const float* Wk   = (const float*)d_in[6];
  const float* Wv   = (const float*)d_in[7];
  float* out = (float*)d_out;

  char* p = (char*)d_ws;
  auto alloc = [&](size_t b) { char* r = p; p += (b + 255) & ~(size_t)255; return (void*)r; };
  int*   cnt     = (int*)alloc((size_t)NTOT * 4);
  int*   row_ptr = (int*)alloc((size_t)(NTOT + 1) * 4);
  int*   cursor  = (int*)alloc((size_t)NTOT * 4);
  int*   bsums   = (int*)alloc(128 * 4);
  int*   boffs   = (int*)alloc(128 * 4);
  int*   ecols   = (int*)alloc((size_t)NEDGE * 4);
  float* evals   = (float*)alloc((size_t)NEDGE * 4);
  uint32* Wbg  = (uint32*)alloc((size_t)12288 * 4);
  float*  Q    = (float*)alloc((size_t)NTOT * 64 * 4);   // QKV Q; reused as GCN1 out
  uint32* KVb  = (uint32*)alloc((size_t)NTOT * 64 * 4);  // 256 B/node
  float*  embA = (float*)alloc((size_t)NTOT * 64 * 4);   // GT1 fp32 out (kept for final sum)
  float*  embB = (float*)alloc((size_t)NTOT * 64 * 4);   // GT2 fp32 out
  uint32* embb0 = (uint32*)alloc((size_t)NTOT * 32 * 4); // bf16 pairs
  uint32* embb1 = (uint32*)alloc((size_t)NTOT * 32 * 4);

  hipMemsetAsync(cnt, 0, (size_t)NTOT * 4, stream);
  k_hist<<<(NEDGE + 255) / 256, 256, 0, stream>>>(rows, cnt);
  int nblk = (NTOT + 2047) / 2048;  // 74
  k_scan1<<<nblk, 256, 0, stream>>>(cnt, row_ptr, bsums);
  k_scan2<<<1, 128, 0, stream>>>(bsums, boffs, nblk);
  k_scan3<<<(NTOT + 255) / 256, 256, 0, stream>>>(row_ptr, boffs, cursor);
  k_fill<<<(NEDGE + 255) / 256, 256, 0, stream>>>(rows, cols, vals, cursor, ecols, evals);
  k_wpack<<<48, 256, 0, stream>>>(Wq, Wk, Wv, Wbg);
  k_init<<<(NTOT * 16 + 255) / 256, 256, 0, stream>>>(ue, ie, embb0);

  // GT layer 1: writes embA (fp32, for final sum) + embb1 (bf16, feeds GT2)
  k_qkv<<<(NTILE + 3) / 4, 256, 0, stream>>>(embb0, Wbg, Q, KVb);
  k_gt<<<(NTOT + 3) / 4, 256, 0, stream>>>(Q, KVb, row_ptr, ecols, embA, embb1);
  // GT layer 2: writes embB (fp32, feeds GCN1 + final sum) + embb0 (unused, cheap)
  k_qkv<<<(NTILE + 3) / 4, 256, 0, stream>>>(embb1, Wbg + 6144, Q, KVb);
  k_gt<<<(NTOT + 3) / 4, 256, 0, stream>>>(Q, KVb, row_ptr, ecols, embB, embb0);
  // GCN1: embB -> Q buffer (Q dead after GT2)
  k_gcn<0><<<(NTOT + 3) / 4, 256, 0, stream>>>(embB, row_ptr, ecols, evals, Q,
                                               nullptr, nullptr, nullptr, nullptr);
  // GCN2 + fused final sum -> out
  k_gcn<1><<<(NTOT + 3) / 4, 256, 0, stream>>>(Q, row_ptr, ecols, evals, out,
                                               ue, ie, embA, embB);
}